// Round 2
// baseline (246.605 us; speedup 1.0000x reference)
//
#include <hip/hip_runtime.h>
#include <hip/hip_bf16.h>
#include <stdint.h>

#define H_ 16
#define DH_ 64
#define B_ 8
#define S_ 1024
#define D_ 1024

using bf16 = __hip_bfloat16;
typedef __attribute__((ext_vector_type(8))) short bfrag;   // 8 x bf16 (16B) MFMA A/B frag
typedef __attribute__((ext_vector_type(4))) float facc;    // 4 x f32 MFMA C/D frag
typedef __attribute__((ext_vector_type(4))) float f4;

// ---------------- f32 -> bf16 bulk convert ----------------
__global__ __launch_bounds__(256) void convert_f32_bf16(const float* __restrict__ in,
                                                        bf16* __restrict__ outb) {
  int i = blockIdx.x * 256 + threadIdx.x;   // one thread = 8 elements
  f4 a = ((const f4*)in)[2 * i];
  f4 b = ((const f4*)in)[2 * i + 1];
  alignas(16) bf16 tmp[8];
#pragma unroll
  for (int j = 0; j < 4; ++j) tmp[j] = __float2bfloat16(a[j]);
#pragma unroll
  for (int j = 0; j < 4; ++j) tmp[4 + j] = __float2bfloat16(b[j]);
  *(bfrag*)&outb[8 * i] = *(const bfrag*)tmp;
}

// ---------------- W transpose f32->bf16 (+ scale folded in) ----------------
// W: (K=1024, N=1024) f32 row-major -> WT: (N, K) bf16 row-major. scale=0.125 for WQ.
__global__ __launch_bounds__(256) void transpose_w(const float* __restrict__ W,
                                                   bf16* __restrict__ WT,
                                                   float scale) {
  __shared__ bf16 tile[32][33];
  int tx = threadIdx.x & 31, ty = threadIdx.x >> 5;  // 32 x 8
  int bx = blockIdx.x, by = blockIdx.y;
#pragma unroll
  for (int i = 0; i < 4; ++i) {
    int kk = by * 32 + ty + 8 * i;
    int nn = bx * 32 + tx;
    tile[ty + 8 * i][tx] = __float2bfloat16(W[kk * D_ + nn] * scale);
  }
  __syncthreads();
#pragma unroll
  for (int i = 0; i < 4; ++i) {
    int nn = bx * 32 + ty + 8 * i;
    int kk = by * 32 + tx;
    WT[(size_t)nn * D_ + kk] = tile[tx][ty + 8 * i];
  }
}

// ---------------- Projection GEMM (all-bf16) ----------------
// A: (M=8192, 1024) row-major bf16; Bt: (1024 n, 1024 k) row-major bf16 (W^T)
// MODE 0: C[m,n] -> out (B,H,S,DH)   (q and k)
// MODE 1: C[m,n] -> out (B,H,DH,S)   (v transposed for the PV B-operand)
template <int MODE>
__global__ __launch_bounds__(256) void proj_gemm(const bf16* __restrict__ A,
                                                 const bf16* __restrict__ Bt,
                                                 bf16* __restrict__ out) {
  __shared__ bf16 As[128][32];
  __shared__ bf16 Bs[128][32];
  int tid = threadIdx.x;
  int lane = tid & 63;
  int wave = tid >> 6;
  int m0 = blockIdx.x * 128;
  int n0 = blockIdx.y * 128;
  int wm = (wave >> 1) * 64;
  int wn = (wave & 1) * 64;
  int l15 = lane & 15, l4 = lane >> 4;
  int srow = tid >> 2;          // 0..63
  int scol = (tid & 3) * 8;     // 0,8,16,24

  facc acc[4][4] = {};

  for (int k0 = 0; k0 < D_; k0 += 32) {
    bfrag a0 = *(const bfrag*)&A[(size_t)(m0 + srow) * D_ + k0 + scol];
    bfrag a1 = *(const bfrag*)&A[(size_t)(m0 + srow + 64) * D_ + k0 + scol];
    bfrag b0 = *(const bfrag*)&Bt[(size_t)(n0 + srow) * D_ + k0 + scol];
    bfrag b1 = *(const bfrag*)&Bt[(size_t)(n0 + srow + 64) * D_ + k0 + scol];
    __syncthreads();   // previous iteration's LDS reads done
    *(bfrag*)&As[srow][scol] = a0;
    *(bfrag*)&As[srow + 64][scol] = a1;
    *(bfrag*)&Bs[srow][scol] = b0;
    *(bfrag*)&Bs[srow + 64][scol] = b1;
    __syncthreads();
    bfrag af[4], bfr[4];
#pragma unroll
    for (int i = 0; i < 4; ++i) af[i] = *(const bfrag*)&As[wm + i * 16 + l15][l4 * 8];
#pragma unroll
    for (int j = 0; j < 4; ++j) bfr[j] = *(const bfrag*)&Bs[wn + j * 16 + l15][l4 * 8];
#pragma unroll
    for (int i = 0; i < 4; ++i)
#pragma unroll
      for (int j = 0; j < 4; ++j)
        acc[i][j] = __builtin_amdgcn_mfma_f32_16x16x32_bf16(af[i], bfr[j], acc[i][j], 0, 0, 0);
  }

  // epilogue: C/D layout col = lane&15, row = (lane>>4)*4 + reg  [m89-verified]
#pragma unroll
  for (int i = 0; i < 4; ++i)
#pragma unroll
    for (int j = 0; j < 4; ++j)
#pragma unroll
      for (int r = 0; r < 4; ++r) {
        int gm = m0 + wm + i * 16 + l4 * 4 + r;   // global row in (B*S)
        int gn = n0 + wn + j * 16 + l15;          // global col in (H*DH)
        int b = gm >> 10, s = gm & (S_ - 1);
        int h = gn >> 6, dh = gn & 63;
        bf16 val = __float2bfloat16(acc[i][j][r]);
        if (MODE == 0)
          out[(((size_t)b * H_ + h) * S_ + s) * DH_ + dh] = val;
        else
          out[(((size_t)b * H_ + h) * DH_ + dh) * S_ + s] = val;
      }
}

// ---------------- Flash attention ----------------
// q,k: (B,H,S,DH) bf16 (q pre-scaled by 1/8 via WQ^T); vT: (B,H,DH,S) bf16
// out: (B,S,H*DH) f32
__global__ __launch_bounds__(256) void attn_fwd(const bf16* __restrict__ q,
                                                const bf16* __restrict__ k,
                                                const bf16* __restrict__ vT,
                                                const int* __restrict__ Qlen,
                                                const int* __restrict__ Vlen,
                                                float* __restrict__ out) {
  __shared__ bf16 p_lds[4][16][32];   // per-wave P transpose buffer
  int tid = threadIdx.x, lane = tid & 63, wave = tid >> 6;
  int bid = blockIdx.x;
  int qt = bid & 15;          // S/64 = 16 q-tiles
  int h = (bid >> 4) & 15;
  int b = bid >> 8;
  int q0 = qt * 64 + wave * 16;   // this wave's 16 q rows
  const bf16* qp = q + (size_t)(b * H_ + h) * S_ * DH_;
  const bf16* kp = k + (size_t)(b * H_ + h) * S_ * DH_;
  const bf16* vp = vT + (size_t)(b * H_ + h) * DH_ * S_;
  int Vl = Vlen[b], Ql = Qlen[b];
  bool vzero = (Vl == 0);
  int l15 = lane & 15, l4 = lane >> 4;

  // Q A-fragments: row = lane&15, k = (lane>>4)*8 + j
  bfrag qf0 = *(const bfrag*)&qp[(q0 + l15) * DH_ + l4 * 8];
  bfrag qf1 = *(const bfrag*)&qp[(q0 + l15) * DH_ + 32 + l4 * 8];

  facc o[4] = {};                     // 4 dh-tiles, rows = (lane>>4)*4+r
  float mrow[4] = {-1e30f, -1e30f, -1e30f, -1e30f};
  float lrow[4] = {0.f, 0.f, 0.f, 0.f};

  int kend = q0 + 16;                          // causal bound for this wave
  if (!vzero) kend = kend < Vl ? kend : Vl;    // V_len>=1: later keys are softmax-zeros
  int nblk = (kend + 31) >> 5;

  for (int kb = 0; kb < nblk; ++kb) {
    int kbase = kb * 32;
    facc z0 = {}, z1 = {};
    {
      bfrag kf0  = *(const bfrag*)&kp[(kbase + l15) * DH_ + l4 * 8];
      bfrag kf0b = *(const bfrag*)&kp[(kbase + l15) * DH_ + 32 + l4 * 8];
      z0 = __builtin_amdgcn_mfma_f32_16x16x32_bf16(qf0, kf0, z0, 0, 0, 0);
      z0 = __builtin_amdgcn_mfma_f32_16x16x32_bf16(qf1, kf0b, z0, 0, 0, 0);
      bfrag kf1  = *(const bfrag*)&kp[(kbase + 16 + l15) * DH_ + l4 * 8];
      bfrag kf1b = *(const bfrag*)&kp[(kbase + 16 + l15) * DH_ + 32 + l4 * 8];
      z1 = __builtin_amdgcn_mfma_f32_16x16x32_bf16(qf0, kf1, z1, 0, 0, 0);
      z1 = __builtin_amdgcn_mfma_f32_16x16x32_bf16(qf1, kf1b, z1, 0, 0, 0);
    }
    int j0 = kbase + l15;        // key index for z0 (col = lane&15)
    int j1 = kbase + 16 + l15;   // key index for z1
#pragma unroll
    for (int r = 0; r < 4; ++r) {
      int qrow = q0 + l4 * 4 + r;
      float sv0 = z0[r], sv1 = z1[r];
      if (vzero) {
        // all keys kv-masked: reference degenerates to exact uniform over j<=q
        sv0 = (j0 <= qrow) ? 0.f : -1e12f;
        sv1 = (j1 <= qrow) ? 0.f : -1e12f;
      } else {
        if (j0 > qrow || j0 >= Vl) sv0 = -1e12f;
        if (j1 > qrow || j1 >= Vl) sv1 = -1e12f;
      }
      float mx = fmaxf(sv0, sv1);
      mx = fmaxf(mx, __shfl_xor(mx, 1, 64));
      mx = fmaxf(mx, __shfl_xor(mx, 2, 64));
      mx = fmaxf(mx, __shfl_xor(mx, 4, 64));
      mx = fmaxf(mx, __shfl_xor(mx, 8, 64));
      float nm = fmaxf(mrow[r], mx);
      float sc = __expf(mrow[r] - nm);
      float p0 = __expf(sv0 - nm);
      float p1 = __expf(sv1 - nm);
      float ss = p0 + p1;
      ss += __shfl_xor(ss, 1, 64);
      ss += __shfl_xor(ss, 2, 64);
      ss += __shfl_xor(ss, 4, 64);
      ss += __shfl_xor(ss, 8, 64);
      lrow[r] = lrow[r] * sc + ss;
      mrow[r] = nm;
      o[0][r] *= sc; o[1][r] *= sc; o[2][r] *= sc; o[3][r] *= sc;
      p_lds[wave][l4 * 4 + r][l15]      = __float2bfloat16(p0);
      p_lds[wave][l4 * 4 + r][16 + l15] = __float2bfloat16(p1);
    }
    // intra-wave LDS transpose round-trip: drain ds_writes, then read A-frag
    asm volatile("s_waitcnt lgkmcnt(0)" ::: "memory");
    bfrag pf = *(const bfrag*)&p_lds[wave][l15][l4 * 8];
#pragma unroll
    for (int t = 0; t < 4; ++t) {
      // V B-frag: col(dh) = lane&15, k = (lane>>4)*8+j, contiguous in vT(DH,S)
      bfrag vf = *(const bfrag*)&vp[(size_t)(t * 16 + l15) * S_ + kbase + l4 * 8];
      o[t] = __builtin_amdgcn_mfma_f32_16x16x32_bf16(pf, vf, o[t], 0, 0, 0);
    }
  }

#pragma unroll
  for (int r = 0; r < 4; ++r) {
    int qrow = q0 + l4 * 4 + r;
    float inv = 1.0f / lrow[r];   // lrow >= 1 always (diagonal key or uniform path)
    bool qmask = (qrow >= Ql);
#pragma unroll
    for (int t = 0; t < 4; ++t) {
      float val = o[t][r] * inv;
      if (qmask) val = 0.f;
      out[((size_t)b * S_ + qrow) * (H_ * DH_) + h * DH_ + t * 16 + l15] = val;
    }
  }
}

extern "C" void kernel_launch(void* const* d_in, const int* in_sizes, int n_in,
                              void* d_out, int out_size, void* d_ws, size_t ws_size,
                              hipStream_t stream) {
  const float* Qs = (const float*)d_in[0];
  const float* Ks = (const float*)d_in[1];
  const float* Vs = (const float*)d_in[2];
  const int* Qlen = (const int*)d_in[3];
  const int* Vlen = (const int*)d_in[4];
  const float* WQ = (const float*)d_in[5];
  const float* WK = (const float*)d_in[6];
  const float* WV = (const float*)d_in[7];
  float* out = (float*)d_out;

  char* ws = (char*)d_ws;
  const size_t MB = 1024 * 1024;
  bf16* wqT = (bf16*)(ws + 0 * MB);    // 2 MB each
  bf16* wkT = (bf16*)(ws + 2 * MB);
  bf16* wvT = (bf16*)(ws + 4 * MB);
  bf16* qb  = (bf16*)(ws + 6 * MB);    // 16 MB each, (B,H,S,DH)
  bf16* kb  = (bf16*)(ws + 22 * MB);
  bf16* vb  = (bf16*)(ws + 38 * MB);   // (B,H,DH,S)
  bf16* xc  = (bf16*)(ws + 54 * MB);   // 16 MB convert buffer (B*S, D) bf16

  dim3 tb(256);
  // fold 1/sqrt(DH)=1/8 into WQ^T (exact bf16 exponent shift)
  transpose_w<<<dim3(32, 32), tb, 0, stream>>>(WQ, wqT, 0.125f);
  transpose_w<<<dim3(32, 32), tb, 0, stream>>>(WK, wkT, 1.0f);
  transpose_w<<<dim3(32, 32), tb, 0, stream>>>(WV, wvT, 1.0f);

  const int CVT_GRID = (B_ * S_ * D_) / (8 * 256);   // 4096
  convert_f32_bf16<<<dim3(CVT_GRID), tb, 0, stream>>>(Qs, xc);
  proj_gemm<0><<<dim3(64, 8), tb, 0, stream>>>(xc, wqT, qb);
  convert_f32_bf16<<<dim3(CVT_GRID), tb, 0, stream>>>(Ks, xc);
  proj_gemm<0><<<dim3(64, 8), tb, 0, stream>>>(xc, wkT, kb);
  convert_f32_bf16<<<dim3(CVT_GRID), tb, 0, stream>>>(Vs, xc);
  proj_gemm<1><<<dim3(64, 8), tb, 0, stream>>>(xc, wvT, vb);

  attn_fwd<<<dim3(B_ * H_ * (S_ / 64)), tb, 0, stream>>>(qb, kb, vb, Qlen, Vlen, out);
}

// Round 3
// 227.867 us; speedup vs baseline: 1.0822x; 1.0822x over previous
//
#include <hip/hip_runtime.h>
#include <hip/hip_bf16.h>
#include <stdint.h>

#define H_ 16
#define DH_ 64
#define B_ 8
#define S_ 1024
#define D_ 1024

using bf16 = __hip_bfloat16;
typedef __attribute__((ext_vector_type(8))) short bfrag;   // 8 x bf16 (16B) MFMA A/B frag
typedef __attribute__((ext_vector_type(4))) float facc;    // 4 x f32 MFMA C/D frag
typedef __attribute__((ext_vector_type(4))) float f4;

// ---------------- f32 -> bf16 bulk convert ----------------
__global__ __launch_bounds__(256) void convert_f32_bf16(const float* __restrict__ in,
                                                        bf16* __restrict__ outb) {
  int i = blockIdx.x * 256 + threadIdx.x;   // one thread = 8 elements
  f4 a = ((const f4*)in)[2 * i];
  f4 b = ((const f4*)in)[2 * i + 1];
  alignas(16) bf16 tmp[8];
#pragma unroll
  for (int j = 0; j < 4; ++j) tmp[j] = __float2bfloat16(a[j]);
#pragma unroll
  for (int j = 0; j < 4; ++j) tmp[4 + j] = __float2bfloat16(b[j]);
  *(bfrag*)&outb[8 * i] = *(const bfrag*)tmp;
}

// ---------------- W transpose f32->bf16 (+ scale folded in) ----------------
__global__ __launch_bounds__(256) void transpose_w(const float* __restrict__ W,
                                                   bf16* __restrict__ WT,
                                                   float scale) {
  __shared__ bf16 tile[32][33];
  int tx = threadIdx.x & 31, ty = threadIdx.x >> 5;  // 32 x 8
  int bx = blockIdx.x, by = blockIdx.y;
#pragma unroll
  for (int i = 0; i < 4; ++i) {
    int kk = by * 32 + ty + 8 * i;
    int nn = bx * 32 + tx;
    tile[ty + 8 * i][tx] = __float2bfloat16(W[kk * D_ + nn] * scale);
  }
  __syncthreads();
#pragma unroll
  for (int i = 0; i < 4; ++i) {
    int nn = bx * 32 + ty + 8 * i;
    int kk = by * 32 + tx;
    WT[(size_t)nn * D_ + kk] = tile[tx][ty + 8 * i];
  }
}

// ---------------- Projection GEMM (m97-style global_load_lds staging) ----------------
// A: (8192, 1024) bf16 row-major; Bt: (1024 n, 1024 k) bf16 row-major (W^T)
// MODE 0: C[m,n] -> out (B,H,S,DH) ; MODE 1: C[m,n] -> out (B,H,DH,S)
template <int MODE>
__global__ __launch_bounds__(256) void proj_gemm(const bf16* __restrict__ A,
                                                 const bf16* __restrict__ Bt,
                                                 bf16* __restrict__ out) {
  __shared__ bf16 As[128][32];
  __shared__ bf16 Bs[128][32];
  int tid = threadIdx.x;
  int lane = tid & 63;
  int wave = tid >> 6;
  int m0 = blockIdx.x * 128;
  int n0 = blockIdx.y * 128;
  int wm = (wave >> 1) * 64;
  int wn = (wave & 1) * 64;
  int l15 = lane & 15, l4 = lane >> 4;
  int lr = lane >> 2;          // row within a 16-row staging group
  int lc = (lane & 3) * 8;     // col elems

  facc acc[4][4] = {};

  for (int k0 = 0; k0 < D_; k0 += 32) {
    __syncthreads();   // all waves done reading As/Bs from prev iter
#pragma unroll
    for (int c = 0; c < 2; ++c) {
      int row = wave * 32 + c * 16;
      __builtin_amdgcn_global_load_lds(
          (const __attribute__((address_space(1))) void*)&A[(size_t)(m0 + row + lr) * D_ + k0 + lc],
          (__attribute__((address_space(3))) void*)&As[row][0], 16, 0, 0);
      __builtin_amdgcn_global_load_lds(
          (const __attribute__((address_space(1))) void*)&Bt[(size_t)(n0 + row + lr) * D_ + k0 + lc],
          (__attribute__((address_space(3))) void*)&Bs[row][0], 16, 0, 0);
    }
    __syncthreads();   // vmcnt drained at barrier -> LDS tiles ready
    bfrag af[4], bfr[4];
#pragma unroll
    for (int i = 0; i < 4; ++i) af[i] = *(const bfrag*)&As[wm + i * 16 + l15][l4 * 8];
#pragma unroll
    for (int j = 0; j < 4; ++j) bfr[j] = *(const bfrag*)&Bs[wn + j * 16 + l15][l4 * 8];
#pragma unroll
    for (int i = 0; i < 4; ++i)
#pragma unroll
      for (int j = 0; j < 4; ++j)
        acc[i][j] = __builtin_amdgcn_mfma_f32_16x16x32_bf16(af[i], bfr[j], acc[i][j], 0, 0, 0);
  }

#pragma unroll
  for (int i = 0; i < 4; ++i)
#pragma unroll
    for (int j = 0; j < 4; ++j)
#pragma unroll
      for (int r = 0; r < 4; ++r) {
        int gm = m0 + wm + i * 16 + l4 * 4 + r;
        int gn = n0 + wn + j * 16 + l15;
        int b = gm >> 10, s = gm & (S_ - 1);
        int h = gn >> 6, dh = gn & 63;
        bf16 val = __float2bfloat16(acc[i][j][r]);
        if (MODE == 0)
          out[(((size_t)b * H_ + h) * S_ + s) * DH_ + dh] = val;
        else
          out[(((size_t)b * H_ + h) * DH_ + dh) * S_ + s] = val;
      }
}

// ---------------- Flash attention, swapped-QK^T, lane-local softmax ----------------
// q,k: (B,H,S,DH) bf16 (q pre-scaled by 1/8); vT: (B,H,DH,S) bf16; out: (B,S,H*DH) f32
// 128-thread blocks (2 waves, 16 q-rows each). qt in HIGH bits of bid for CU balance.
__global__ __launch_bounds__(128) void attn_fwd(const bf16* __restrict__ q,
                                                const bf16* __restrict__ k,
                                                const bf16* __restrict__ vT,
                                                const int* __restrict__ Qlen,
                                                const int* __restrict__ Vlen,
                                                float* __restrict__ out) {
  int lane = threadIdx.x & 63, wave = threadIdx.x >> 6;
  int bid = blockIdx.x;
  int qt = bid >> 7;           // 0..31 : 32-row tile index (high bits -> balance)
  int b = (bid >> 4) & 7;
  int h = bid & 15;
  int q0 = qt * 32 + wave * 16;
  const bf16* qp = q + (size_t)(b * H_ + h) * S_ * DH_;
  const bf16* kp = k + (size_t)(b * H_ + h) * S_ * DH_;
  const bf16* vp = vT + (size_t)(b * H_ + h) * DH_ * S_;
  int Vl = Vlen[b], Ql = Qlen[b];
  bool vzero = (Vl == 0);   // -1e12 shift is uniform in f32 -> exact uniform softmax
  int l15 = lane & 15, g = lane >> 4;
  int qrow = q0 + l15;      // this lane's single q row

  // Q as B-operand: col = lane&15 = q, d = g*8 + j
  bfrag qf0 = *(const bfrag*)&qp[(q0 + l15) * DH_ + g * 8];
  bfrag qf1 = *(const bfrag*)&qp[(q0 + l15) * DH_ + 32 + g * 8];

  facc o[4] = {};              // O^T accum: col=q(lane&15), row d = 16t + 4g + r
  float mrow = -1e30f, lrow = 0.f;

  int kend = q0 + 16;
  if (!vzero) kend = kend < Vl ? kend : Vl;
  int nblk = (kend + 31) >> 5;
  // permuted K A-row: row rr holds key 8*(rr>>2)+(rr&3)  (kf1: +4)
  int krow0 = 8 * (l15 >> 2) + (l15 & 3);

  for (int kb = 0; kb < nblk; ++kb) {
    int kbase = kb * 32;
    const bf16* klo = &kp[(size_t)(kbase + krow0) * DH_];
    const bf16* khi = &kp[(size_t)(kbase + krow0 + 4) * DH_];
    bfrag kf0  = *(const bfrag*)&klo[g * 8];
    bfrag kf0b = *(const bfrag*)&klo[32 + g * 8];
    bfrag kf1  = *(const bfrag*)&khi[g * 8];
    bfrag kf1b = *(const bfrag*)&khi[32 + g * 8];
    facc z0 = {}, z1 = {};
    z0 = __builtin_amdgcn_mfma_f32_16x16x32_bf16(kf0, qf0, z0, 0, 0, 0);
    z0 = __builtin_amdgcn_mfma_f32_16x16x32_bf16(kf0b, qf1, z0, 0, 0, 0);
    z1 = __builtin_amdgcn_mfma_f32_16x16x32_bf16(kf1, qf0, z1, 0, 0, 0);
    z1 = __builtin_amdgcn_mfma_f32_16x16x32_bf16(kf1b, qf1, z1, 0, 0, 0);

    // lane holds keys jb..jb+7 for its q column
    int jb = kbase + 8 * g;
    float sv[8];
#pragma unroll
    for (int c = 0; c < 4; ++c) { sv[c] = z0[c]; sv[4 + c] = z1[c]; }
#pragma unroll
    for (int c = 0; c < 8; ++c) {
      int j = jb + c;
      if (vzero)
        sv[c] = (j <= qrow) ? 0.f : -1e12f;
      else if (j > qrow || j >= Vl)
        sv[c] = -1e12f;
    }
    float mx = sv[0];
#pragma unroll
    for (int c = 1; c < 8; ++c) mx = fmaxf(mx, sv[c]);
    mx = fmaxf(mx, __shfl_xor(mx, 16, 64));
    mx = fmaxf(mx, __shfl_xor(mx, 32, 64));
    float nm = fmaxf(mrow, mx);
    float sc = __expf(mrow - nm);
    alignas(16) bf16 pb[8];
    float ss = 0.f;
#pragma unroll
    for (int c = 0; c < 8; ++c) {
      float pv = __expf(sv[c] - nm);
      ss += pv;
      pb[c] = __float2bfloat16(pv);
    }
    ss += __shfl_xor(ss, 16, 64);
    ss += __shfl_xor(ss, 32, 64);
    lrow = lrow * sc + ss;
    mrow = nm;
#pragma unroll
    for (int t = 0; t < 4; ++t)
#pragma unroll
      for (int r = 0; r < 4; ++r) o[t][r] *= sc;

    bfrag pf = *(const bfrag*)pb;   // B-operand: col=q(lane&15), k = g*8+j  — exact match
#pragma unroll
    for (int t = 0; t < 4; ++t) {
      // V^T as A-operand: row = d(lane&15 within tile t), k = g*8+j, contiguous in vT
      bfrag vf = *(const bfrag*)&vp[(size_t)(t * 16 + l15) * S_ + kbase + g * 8];
      o[t] = __builtin_amdgcn_mfma_f32_16x16x32_bf16(vf, pf, o[t], 0, 0, 0);
    }
  }

  float inv = 1.0f / lrow;
  if (qrow >= Ql) inv = 0.f;     // query-length mask
#pragma unroll
  for (int t = 0; t < 4; ++t) {
    f4 ov;
#pragma unroll
    for (int r = 0; r < 4; ++r) ov[r] = o[t][r] * inv;
    *(f4*)&out[((size_t)b * S_ + qrow) * (H_ * DH_) + h * DH_ + t * 16 + g * 4] = ov;
  }
}

extern "C" void kernel_launch(void* const* d_in, const int* in_sizes, int n_in,
                              void* d_out, int out_size, void* d_ws, size_t ws_size,
                              hipStream_t stream) {
  const float* Qs = (const float*)d_in[0];
  const float* Ks = (const float*)d_in[1];
  const float* Vs = (const float*)d_in[2];
  const int* Qlen = (const int*)d_in[3];
  const int* Vlen = (const int*)d_in[4];
  const float* WQ = (const float*)d_in[5];
  const float* WK = (const float*)d_in[6];
  const float* WV = (const float*)d_in[7];
  float* out = (float*)d_out;

  char* ws = (char*)d_ws;
  const size_t MB = 1024 * 1024;
  bf16* wqT = (bf16*)(ws + 0 * MB);
  bf16* wkT = (bf16*)(ws + 2 * MB);
  bf16* wvT = (bf16*)(ws + 4 * MB);
  bf16* qb  = (bf16*)(ws + 6 * MB);    // (B,H,S,DH)
  bf16* kb  = (bf16*)(ws + 22 * MB);
  bf16* vb  = (bf16*)(ws + 38 * MB);   // (B,H,DH,S)
  bf16* xc  = (bf16*)(ws + 54 * MB);   // (B*S, D) bf16 convert buffer

  dim3 tb(256);
  transpose_w<<<dim3(32, 32), tb, 0, stream>>>(WQ, wqT, 0.125f);  // fold 1/sqrt(64)
  transpose_w<<<dim3(32, 32), tb, 0, stream>>>(WK, wkT, 1.0f);
  transpose_w<<<dim3(32, 32), tb, 0, stream>>>(WV, wvT, 1.0f);

  const int CVT_GRID = (B_ * S_ * D_) / (8 * 256);
  convert_f32_bf16<<<dim3(CVT_GRID), tb, 0, stream>>>(Qs, xc);
  proj_gemm<0><<<dim3(64, 8), tb, 0, stream>>>(xc, wqT, qb);
  convert_f32_bf16<<<dim3(CVT_GRID), tb, 0, stream>>>(Ks, xc);
  proj_gemm<0><<<dim3(64, 8), tb, 0, stream>>>(xc, wkT, kb);
  convert_f32_bf16<<<dim3(CVT_GRID), tb, 0, stream>>>(Vs, xc);
  proj_gemm<1><<<dim3(64, 8), tb, 0, stream>>>(xc, wvT, vb);

  attn_fwd<<<dim3(B_ * H_ * (S_ / 32)), dim3(128), 0, stream>>>(qb, kb, vb, Qlen, Vlen, out);
}

// Round 4
// 166.429 us; speedup vs baseline: 1.4817x; 1.3692x over previous
//
#include <hip/hip_runtime.h>
#include <hip/hip_bf16.h>
#include <stdint.h>

#define H_ 16
#define DH_ 64
#define B_ 8
#define S_ 1024
#define D_ 1024

using bf16 = __hip_bfloat16;
typedef __attribute__((ext_vector_type(8))) short bfrag;   // 8 x bf16 (16B) MFMA A/B frag
typedef __attribute__((ext_vector_type(4))) float facc;    // 4 x f32 MFMA C/D frag
typedef __attribute__((ext_vector_type(4))) float f4;

#define SWZ(r) ((((r) & 7) << 4) ^ (((r) & 8) << 3))

// ---------------- f32 -> bf16 bulk convert ----------------
__global__ __launch_bounds__(256) void convert_f32_bf16(const float* __restrict__ in,
                                                        bf16* __restrict__ outb) {
  int i = blockIdx.x * 256 + threadIdx.x;   // one thread = 8 elements
  f4 a = ((const f4*)in)[2 * i];
  f4 b = ((const f4*)in)[2 * i + 1];
  alignas(16) bf16 tmp[8];
#pragma unroll
  for (int j = 0; j < 4; ++j) tmp[j] = __float2bfloat16(a[j]);
#pragma unroll
  for (int j = 0; j < 4; ++j) tmp[4 + j] = __float2bfloat16(b[j]);
  *(bfrag*)&outb[8 * i] = *(const bfrag*)tmp;
}

// ---------------- W transpose f32->bf16 (+ scale folded in) ----------------
__global__ __launch_bounds__(256) void transpose_w(const float* __restrict__ W,
                                                   bf16* __restrict__ WT,
                                                   float scale) {
  __shared__ bf16 tile[32][33];
  int tx = threadIdx.x & 31, ty = threadIdx.x >> 5;  // 32 x 8
  int bx = blockIdx.x, by = blockIdx.y;
#pragma unroll
  for (int i = 0; i < 4; ++i) {
    int kk = by * 32 + ty + 8 * i;
    int nn = bx * 32 + tx;
    tile[ty + 8 * i][tx] = __float2bfloat16(W[kk * D_ + nn] * scale);
  }
  __syncthreads();
#pragma unroll
  for (int i = 0; i < 4; ++i) {
    int nn = bx * 32 + ty + 8 * i;
    int kk = by * 32 + tx;
    WT[(size_t)nn * D_ + kk] = tile[tx][ty + 8 * i];
  }
}

// ---------------- Projection GEMM (m97-style global_load_lds staging) ----------------
template <int MODE>
__global__ __launch_bounds__(256) void proj_gemm(const bf16* __restrict__ A,
                                                 const bf16* __restrict__ Bt,
                                                 bf16* __restrict__ out) {
  __shared__ bf16 As[128][32];
  __shared__ bf16 Bs[128][32];
  int tid = threadIdx.x;
  int lane = tid & 63;
  int wave = tid >> 6;
  int m0 = blockIdx.x * 128;
  int n0 = blockIdx.y * 128;
  int wm = (wave >> 1) * 64;
  int wn = (wave & 1) * 64;
  int l15 = lane & 15, l4 = lane >> 4;
  int lr = lane >> 2;
  int lc = (lane & 3) * 8;

  facc acc[4][4] = {};

  for (int k0 = 0; k0 < D_; k0 += 32) {
    __syncthreads();
#pragma unroll
    for (int c = 0; c < 2; ++c) {
      int row = wave * 32 + c * 16;
      __builtin_amdgcn_global_load_lds(
          (const __attribute__((address_space(1))) void*)&A[(size_t)(m0 + row + lr) * D_ + k0 + lc],
          (__attribute__((address_space(3))) void*)&As[row][0], 16, 0, 0);
      __builtin_amdgcn_global_load_lds(
          (const __attribute__((address_space(1))) void*)&Bt[(size_t)(n0 + row + lr) * D_ + k0 + lc],
          (__attribute__((address_space(3))) void*)&Bs[row][0], 16, 0, 0);
    }
    __syncthreads();
    bfrag af[4], bfr[4];
#pragma unroll
    for (int i = 0; i < 4; ++i) af[i] = *(const bfrag*)&As[wm + i * 16 + l15][l4 * 8];
#pragma unroll
    for (int j = 0; j < 4; ++j) bfr[j] = *(const bfrag*)&Bs[wn + j * 16 + l15][l4 * 8];
#pragma unroll
    for (int i = 0; i < 4; ++i)
#pragma unroll
      for (int j = 0; j < 4; ++j)
        acc[i][j] = __builtin_amdgcn_mfma_f32_16x16x32_bf16(af[i], bfr[j], acc[i][j], 0, 0, 0);
  }

#pragma unroll
  for (int i = 0; i < 4; ++i)
#pragma unroll
    for (int j = 0; j < 4; ++j)
#pragma unroll
      for (int r = 0; r < 4; ++r) {
        int gm = m0 + wm + i * 16 + l4 * 4 + r;
        int gn = n0 + wn + j * 16 + l15;
        int b = gm >> 10, s = gm & (S_ - 1);
        int h = gn >> 6, dh = gn & 63;
        bf16 val = __float2bfloat16(acc[i][j][r]);
        if (MODE == 0)
          out[(((size_t)b * H_ + h) * S_ + s) * DH_ + dh] = val;
        else
          out[(((size_t)b * H_ + h) * DH_ + dh) * S_ + s] = val;
      }
}

// ---------------- Flash attention: LDS-staged K/V, swapped-QK^T, in-reg P ----------------
// q,k: (B,H,S,DH) bf16 (q pre-scaled 1/8); vT: (B,H,DH,S) bf16; out: (B,S,H*DH) f32
// 256-thr blocks = 4 waves x 16 q-rows = 64-row q-tile; KBLK=64 staged in LDS.
__global__ __launch_bounds__(256) void attn_fwd(const bf16* __restrict__ q,
                                                const bf16* __restrict__ k,
                                                const bf16* __restrict__ vT,
                                                const int* __restrict__ Qlen,
                                                const int* __restrict__ Vlen,
                                                float* __restrict__ out) {
  __shared__ __align__(16) bf16 Kt[64 * 64];   // 8 KB, row = key, 128B/row, XOR-swizzled
  __shared__ __align__(16) bf16 Vt[64 * 64];   // 8 KB, row = d,   128B/row, XOR-swizzled
  int tid = threadIdx.x, lane = tid & 63, wave = tid >> 6;
  int bid = blockIdx.x;
  int h = bid & 15, b = (bid >> 4) & 7, qt = bid >> 7;   // qt in high bits -> CU balance
  int q0b = qt * 64;
  int q0 = q0b + wave * 16;
  const bf16* qp = q + (size_t)(b * H_ + h) * S_ * DH_;
  const bf16* kp = k + (size_t)(b * H_ + h) * S_ * DH_;
  const bf16* vp = vT + (size_t)(b * H_ + h) * DH_ * S_;
  int Vl = Vlen[b], Ql = Qlen[b];
  bool vzero = (Vl == 0);   // f32 ref: A-1e12 == -1e12 exactly -> uniform causal softmax
  int l15 = lane & 15, g = lane >> 4;
  int qrow = q0 + l15;

  // Q as B-operand: col = lane&15 = q, d = g*8 + j
  bfrag qf0 = *(const bfrag*)&qp[(q0 + l15) * DH_ + g * 8];
  bfrag qf1 = *(const bfrag*)&qp[(q0 + l15) * DH_ + 32 + g * 8];

  facc o[4] = {};              // O^T accum: col=q(lane&15), row d = 16t + 4g + r
  float mrow = -1e30f, lrow = 0.f;

  int kendb = q0b + 64;                         // block-level key bound
  if (!vzero) kendb = kendb < Vl ? kendb : Vl;
  int nblk = (kendb + 63) >> 6;

  // permuted K A-row: A-row r holds key 8*(r>>2)+(r&3)
  int krow0 = 8 * (l15 >> 2) + (l15 & 3);
  // staging geometry: this lane stages rows sr0, sr0+8 at byte sbb (pre-swizzled source)
  int sr0 = wave * 16 + (lane >> 3);
  int sbb = (lane & 7) * 16;

  for (int kb = 0; kb < nblk; ++kb) {
    int kbase = kb * 64;
    __syncthreads();   // all waves done with previous tile's LDS reads
    {
      int r0 = sr0, r1 = sr0 + 8;
      const char* kg0 = (const char*)(kp + (size_t)(kbase + r0) * DH_) + (sbb ^ SWZ(r0));
      const char* kg1 = (const char*)(kp + (size_t)(kbase + r1) * DH_) + (sbb ^ SWZ(r1));
      const char* vg0 = (const char*)(vp + (size_t)r0 * S_ + kbase) + (sbb ^ SWZ(r0));
      const char* vg1 = (const char*)(vp + (size_t)r1 * S_ + kbase) + (sbb ^ SWZ(r1));
      char* kl = (char*)Kt + wave * 2048;
      char* vl = (char*)Vt + wave * 2048;
      __builtin_amdgcn_global_load_lds((const __attribute__((address_space(1))) void*)kg0,
          (__attribute__((address_space(3))) void*)kl, 16, 0, 0);
      __builtin_amdgcn_global_load_lds((const __attribute__((address_space(1))) void*)kg1,
          (__attribute__((address_space(3))) void*)(kl + 1024), 16, 0, 0);
      __builtin_amdgcn_global_load_lds((const __attribute__((address_space(1))) void*)vg0,
          (__attribute__((address_space(3))) void*)vl, 16, 0, 0);
      __builtin_amdgcn_global_load_lds((const __attribute__((address_space(1))) void*)vg1,
          (__attribute__((address_space(3))) void*)(vl + 1024), 16, 0, 0);
    }
    __syncthreads();   // vmcnt drained at barrier -> tiles ready

    // ---- QK^T: 64 keys, swapped operands ----
    facc z[4] = {};
#pragma unroll
    for (int gg = 0; gg < 2; ++gg) {
      int ra = gg * 32 + krow0;
      int rb = ra + 4;
      bfrag a0 = *(const bfrag*)((const char*)Kt + ra * 128 + ((g * 16) ^ SWZ(ra)));
      bfrag a1 = *(const bfrag*)((const char*)Kt + ra * 128 + ((g * 16 + 64) ^ SWZ(ra)));
      z[2 * gg] = __builtin_amdgcn_mfma_f32_16x16x32_bf16(a0, qf0, z[2 * gg], 0, 0, 0);
      z[2 * gg] = __builtin_amdgcn_mfma_f32_16x16x32_bf16(a1, qf1, z[2 * gg], 0, 0, 0);
      bfrag a2 = *(const bfrag*)((const char*)Kt + rb * 128 + ((g * 16) ^ SWZ(rb)));
      bfrag a3 = *(const bfrag*)((const char*)Kt + rb * 128 + ((g * 16 + 64) ^ SWZ(rb)));
      z[2 * gg + 1] = __builtin_amdgcn_mfma_f32_16x16x32_bf16(a2, qf0, z[2 * gg + 1], 0, 0, 0);
      z[2 * gg + 1] = __builtin_amdgcn_mfma_f32_16x16x32_bf16(a3, qf1, z[2 * gg + 1], 0, 0, 0);
    }

    // lane holds 16 keys: group gg -> kbase + 32*gg + 8*g + {0..7}
    float sv[16];
#pragma unroll
    for (int gg = 0; gg < 2; ++gg)
#pragma unroll
      for (int c = 0; c < 4; ++c) {
        sv[8 * gg + c] = z[2 * gg][c];
        sv[8 * gg + 4 + c] = z[2 * gg + 1][c];
      }
#pragma unroll
    for (int gg = 0; gg < 2; ++gg)
#pragma unroll
      for (int c = 0; c < 8; ++c) {
        int j = kbase + 32 * gg + 8 * g + c;
        if (vzero)
          sv[8 * gg + c] = (j <= qrow) ? 0.f : -1e12f;
        else if (j > qrow || j >= Vl)
          sv[8 * gg + c] = -1e12f;
      }

    float mx = sv[0];
#pragma unroll
    for (int c = 1; c < 16; ++c) mx = fmaxf(mx, sv[c]);
    mx = fmaxf(mx, __shfl_xor(mx, 16, 64));
    mx = fmaxf(mx, __shfl_xor(mx, 32, 64));
    float nm = fmaxf(mrow, mx);
    float sc = __expf(mrow - nm);
    alignas(16) bf16 pb[16];
    float ss = 0.f;
#pragma unroll
    for (int c = 0; c < 16; ++c) {
      float pv = __expf(sv[c] - nm);
      ss += pv;
      pb[c] = __float2bfloat16(pv);
    }
    ss += __shfl_xor(ss, 16, 64);
    ss += __shfl_xor(ss, 32, 64);
    lrow = lrow * sc + ss;
    mrow = nm;
#pragma unroll
    for (int t = 0; t < 4; ++t)
#pragma unroll
      for (int r = 0; r < 4; ++r) o[t][r] *= sc;

    // ---- PV: o[t] += V^T x P, V from swizzled LDS ----
    bfrag pf0 = *(const bfrag*)&pb[0];   // keys kbase + 8g + {0..7}
    bfrag pf1 = *(const bfrag*)&pb[8];   // keys kbase + 32 + 8g + {0..7}
#pragma unroll
    for (int t = 0; t < 4; ++t) {
      int d = t * 16 + l15;
      bfrag vf0 = *(const bfrag*)((const char*)Vt + d * 128 + ((g * 16) ^ SWZ(d)));
      bfrag vf1 = *(const bfrag*)((const char*)Vt + d * 128 + ((g * 16 + 64) ^ SWZ(d)));
      o[t] = __builtin_amdgcn_mfma_f32_16x16x32_bf16(vf0, pf0, o[t], 0, 0, 0);
      o[t] = __builtin_amdgcn_mfma_f32_16x16x32_bf16(vf1, pf1, o[t], 0, 0, 0);
    }
  }

  float inv = 1.0f / lrow;
  if (qrow >= Ql) inv = 0.f;     // query-length mask
#pragma unroll
  for (int t = 0; t < 4; ++t) {
    f4 ov;
#pragma unroll
    for (int r = 0; r < 4; ++r) ov[r] = o[t][r] * inv;
    *(f4*)&out[((size_t)b * S_ + qrow) * (H_ * DH_) + h * DH_ + t * 16 + g * 4] = ov;
  }
}

extern "C" void kernel_launch(void* const* d_in, const int* in_sizes, int n_in,
                              void* d_out, int out_size, void* d_ws, size_t ws_size,
                              hipStream_t stream) {
  const float* Qs = (const float*)d_in[0];
  const float* Ks = (const float*)d_in[1];
  const float* Vs = (const float*)d_in[2];
  const int* Qlen = (const int*)d_in[3];
  const int* Vlen = (const int*)d_in[4];
  const float* WQ = (const float*)d_in[5];
  const float* WK = (const float*)d_in[6];
  const float* WV = (const float*)d_in[7];
  float* out = (float*)d_out;

  char* ws = (char*)d_ws;
  const size_t MB = 1024 * 1024;
  bf16* wqT = (bf16*)(ws + 0 * MB);
  bf16* wkT = (bf16*)(ws + 2 * MB);
  bf16* wvT = (bf16*)(ws + 4 * MB);
  bf16* qb  = (bf16*)(ws + 6 * MB);    // (B,H,S,DH)
  bf16* kb  = (bf16*)(ws + 22 * MB);
  bf16* vb  = (bf16*)(ws + 38 * MB);   // (B,H,DH,S)
  bf16* xc  = (bf16*)(ws + 54 * MB);   // (B*S, D) bf16 convert buffer

  dim3 tb(256);
  transpose_w<<<dim3(32, 32), tb, 0, stream>>>(WQ, wqT, 0.125f);  // fold 1/sqrt(64)
  transpose_w<<<dim3(32, 32), tb, 0, stream>>>(WK, wkT, 1.0f);
  transpose_w<<<dim3(32, 32), tb, 0, stream>>>(WV, wvT, 1.0f);

  const int CVT_GRID = (B_ * S_ * D_) / (8 * 256);
  convert_f32_bf16<<<dim3(CVT_GRID), tb, 0, stream>>>(Qs, xc);
  proj_gemm<0><<<dim3(64, 8), tb, 0, stream>>>(xc, wqT, qb);
  convert_f32_bf16<<<dim3(CVT_GRID), tb, 0, stream>>>(Ks, xc);
  proj_gemm<0><<<dim3(64, 8), tb, 0, stream>>>(xc, wkT, kb);
  convert_f32_bf16<<<dim3(CVT_GRID), tb, 0, stream>>>(Vs, xc);
  proj_gemm<1><<<dim3(64, 8), tb, 0, stream>>>(xc, wvT, vb);

  attn_fwd<<<dim3(B_ * H_ * (S_ / 64)), tb, 0, stream>>>(qb, kb, vb, Qlen, Vlen, out);
}

// Round 5
// 163.166 us; speedup vs baseline: 1.5114x; 1.0200x over previous
//
#include <hip/hip_runtime.h>
#include <hip/hip_bf16.h>
#include <stdint.h>

#define H_ 16
#define DH_ 64
#define B_ 8
#define S_ 1024
#define D_ 1024

using bf16 = __hip_bfloat16;
typedef __attribute__((ext_vector_type(8))) short bfrag;   // 8 x bf16 (16B) MFMA A/B frag
typedef __attribute__((ext_vector_type(4))) float facc;    // 4 x f32 MFMA C/D frag
typedef __attribute__((ext_vector_type(4))) float f4;

#define SWZ(r) ((((r) & 7) << 4) ^ (((r) & 8) << 3))

// ---------------- W transpose f32->bf16 (+ scale folded in) ----------------
__global__ __launch_bounds__(256) void transpose_w(const float* __restrict__ W,
                                                   bf16* __restrict__ WT,
                                                   float scale) {
  __shared__ bf16 tile[32][33];
  int tx = threadIdx.x & 31, ty = threadIdx.x >> 5;  // 32 x 8
  int bx = blockIdx.x, by = blockIdx.y;
#pragma unroll
  for (int i = 0; i < 4; ++i) {
    int kk = by * 32 + ty + 8 * i;
    int nn = bx * 32 + tx;
    tile[ty + 8 * i][tx] = __float2bfloat16(W[kk * D_ + nn] * scale);
  }
  __syncthreads();
#pragma unroll
  for (int i = 0; i < 4; ++i) {
    int nn = bx * 32 + ty + 8 * i;
    int kk = by * 32 + tx;
    WT[(size_t)nn * D_ + kk] = tile[tx][ty + 8 * i];
  }
}

// ---------------- Projection GEMM: f32 A (fused convert), double-buffered ----------------
// A: (8192, 1024) f32 row-major; Bt: (1024 n, 1024 k) bf16 row-major (W^T)
// MODE 0: C[m,n] -> out (B,H,S,DH) ; MODE 1: C[m,n] -> out (B,H,DH,S)
template <int MODE>
__global__ __launch_bounds__(256) void proj_gemm(const float* __restrict__ A,
                                                 const bf16* __restrict__ Bt,
                                                 bf16* __restrict__ out) {
  __shared__ bf16 As[2][128][32];
  __shared__ bf16 Bs[2][128][32];
  int tid = threadIdx.x;
  int lane = tid & 63;
  int wave = tid >> 6;
  int m0 = blockIdx.x * 128;
  int n0 = blockIdx.y * 128;
  int wm = (wave >> 1) * 64;
  int wn = (wave & 1) * 64;
  int l15 = lane & 15, l4 = lane >> 4;
  // A reg-staging: thread tid covers rows {ar, ar+64}, 8 f32 cols each
  int ar = tid >> 2;
  int ac = (tid & 3) * 8;
  // B gload_lds staging: wave w stages rows w*32 + c*16 + (lane>>2)
  int br = lane >> 2, bc = (lane & 3) * 8;

  facc acc[4][4] = {};
  f4 ap[4];   // A f32 in flight (16 f32)

  auto issueA = [&](int k0) {
    const float* s0 = &A[(size_t)(m0 + ar) * D_ + k0 + ac];
    ap[0] = *(const f4*)s0;
    ap[1] = *(const f4*)(s0 + 4);
    const float* s1 = &A[(size_t)(m0 + 64 + ar) * D_ + k0 + ac];
    ap[2] = *(const f4*)s1;
    ap[3] = *(const f4*)(s1 + 4);
  };
  auto issueB = [&](int buf, int k0) {
#pragma unroll
    for (int c = 0; c < 2; ++c) {
      int row = wave * 32 + c * 16;
      __builtin_amdgcn_global_load_lds(
          (const __attribute__((address_space(1))) void*)&Bt[(size_t)(n0 + row + br) * D_ + k0 + bc],
          (__attribute__((address_space(3))) void*)&Bs[buf][row][0], 16, 0, 0);
    }
  };
  auto writeA = [&](int buf) {
    alignas(16) bf16 t0[8], t1[8];
#pragma unroll
    for (int j = 0; j < 4; ++j) {
      t0[j] = __float2bfloat16(ap[0][j]);
      t0[4 + j] = __float2bfloat16(ap[1][j]);
      t1[j] = __float2bfloat16(ap[2][j]);
      t1[4 + j] = __float2bfloat16(ap[3][j]);
    }
    // byte addr = tid*16 (and +4096): consecutive 16B per lane -> conflict-free
    *(bfrag*)&As[buf][ar][ac] = *(const bfrag*)t0;
    *(bfrag*)&As[buf][64 + ar][ac] = *(const bfrag*)t1;
  };

  // prologue: stage k-step 0 into buf 0
  issueA(0);
  issueB(0, 0);
  writeA(0);          // compiler inserts vmcnt wait for ap here
  __syncthreads();    // drains B gload_lds (vmcnt) + ds_writes (lgkm)

  for (int kt = 0; kt < 32; ++kt) {
    int cur = kt & 1;
    if (kt < 31) {
      issueA((kt + 1) * 32);
      issueB(1 - cur, (kt + 1) * 32);
    }
    bfrag af[4], bfr[4];
#pragma unroll
    for (int i = 0; i < 4; ++i) af[i] = *(const bfrag*)&As[cur][wm + i * 16 + l15][l4 * 8];
#pragma unroll
    for (int j = 0; j < 4; ++j) bfr[j] = *(const bfrag*)&Bs[cur][wn + j * 16 + l15][l4 * 8];
#pragma unroll
    for (int i = 0; i < 4; ++i)
#pragma unroll
      for (int j = 0; j < 4; ++j)
        acc[i][j] = __builtin_amdgcn_mfma_f32_16x16x32_bf16(af[i], bfr[j], acc[i][j], 0, 0, 0);
    if (kt < 31) writeA(1 - cur);   // ap loads had the whole compute to land
    __syncthreads();                // next tile ready; all waves done with cur
  }

  // epilogue: C/D layout col = lane&15, row = (lane>>4)*4 + reg
#pragma unroll
  for (int i = 0; i < 4; ++i)
#pragma unroll
    for (int j = 0; j < 4; ++j)
#pragma unroll
      for (int r = 0; r < 4; ++r) {
        int gm = m0 + wm + i * 16 + l4 * 4 + r;
        int gn = n0 + wn + j * 16 + l15;
        int b = gm >> 10, s = gm & (S_ - 1);
        int h = gn >> 6, dh = gn & 63;
        bf16 val = __float2bfloat16(acc[i][j][r]);
        if (MODE == 0)
          out[(((size_t)b * H_ + h) * S_ + s) * DH_ + dh] = val;
        else
          out[(((size_t)b * H_ + h) * DH_ + dh) * S_ + s] = val;
      }
}

// ---------------- Flash attention: double-buffered LDS K/V, swapped-QK^T ----------------
// q,k: (B,H,S,DH) bf16 (q pre-scaled by log2e/8); vT: (B,H,DH,S) bf16; out: (B,S,H*DH) f32
__global__ __launch_bounds__(256) void attn_fwd(const bf16* __restrict__ q,
                                                const bf16* __restrict__ k,
                                                const bf16* __restrict__ vT,
                                                const int* __restrict__ Qlen,
                                                const int* __restrict__ Vlen,
                                                float* __restrict__ out) {
  __shared__ __align__(16) bf16 Kt[2][64 * 64];   // 8 KB each, row=key, XOR-swizzled
  __shared__ __align__(16) bf16 Vt[2][64 * 64];   // 8 KB each, row=d,   XOR-swizzled
  int tid = threadIdx.x, lane = tid & 63, wave = tid >> 6;
  int bid = blockIdx.x;
  int h = bid & 15, b = (bid >> 4) & 7, qt = bid >> 7;   // qt in high bits -> CU balance
  int q0b = qt * 64;
  int q0 = q0b + wave * 16;
  const bf16* qp = q + (size_t)(b * H_ + h) * S_ * DH_;
  const bf16* kp = k + (size_t)(b * H_ + h) * S_ * DH_;
  const bf16* vp = vT + (size_t)(b * H_ + h) * DH_ * S_;
  int Vl = Vlen[b], Ql = Qlen[b];
  bool vzero = (Vl == 0);   // f32 ref: A-1e12 == -1e12 exactly -> exact uniform causal softmax
  int l15 = lane & 15, g = lane >> 4;
  int qrow = q0 + l15;

  // per-lane valid-key bound and wave-uniform tile bounds
  int jlim = vzero ? (qrow + 1) : min(qrow + 1, Vl);   // keys j < jlim are live
  int wmin = vzero ? (q0 + 1) : min(q0 + 1, Vl);       // min jlim over wave
  int wmax = vzero ? (q0 + 16) : min(q0 + 16, Vl);     // max jlim over wave

  // Q as B-operand: col = lane&15 = q, d = g*8 + j   (scores in log2 domain)
  bfrag qf0 = *(const bfrag*)&qp[(q0 + l15) * DH_ + g * 8];
  bfrag qf1 = *(const bfrag*)&qp[(q0 + l15) * DH_ + 32 + g * 8];
  if (vzero) {   // scores := 0 -> exact uniform weights over causal window
#pragma unroll
    for (int i = 0; i < 8; ++i) { qf0[i] = 0; qf1[i] = 0; }
  }

  facc o[4] = {};              // O^T accum: col=q(lane&15), row d = 16t + 4g + r
  float mrow = -1e30f, lrow = 0.f;

  int kendb = q0b + 64;                          // block-level key bound
  if (!vzero) kendb = kendb < Vl ? kendb : Vl;
  int nblk = (kendb + 63) >> 6;

  // permuted K A-row: A-row r holds key 8*(r>>2)+(r&3)
  int krow0 = 8 * (l15 >> 2) + (l15 & 3);
  // staging: lane stages rows sr0, sr0+8 at byte sbb (pre-swizzled source, linear LDS dest)
  int sr0 = wave * 16 + (lane >> 3);
  int sbb = (lane & 7) * 16;

  auto stage = [&](int buf, int kbase) {
    int r0 = sr0, r1 = sr0 + 8;
    const char* kg0 = (const char*)(kp + (size_t)(kbase + r0) * DH_) + (sbb ^ SWZ(r0));
    const char* kg1 = (const char*)(kp + (size_t)(kbase + r1) * DH_) + (sbb ^ SWZ(r1));
    const char* vg0 = (const char*)(vp + (size_t)r0 * S_ + kbase) + (sbb ^ SWZ(r0));
    const char* vg1 = (const char*)(vp + (size_t)r1 * S_ + kbase) + (sbb ^ SWZ(r1));
    char* kl = (char*)&Kt[buf][0] + wave * 2048;
    char* vl = (char*)&Vt[buf][0] + wave * 2048;
    __builtin_amdgcn_global_load_lds((const __attribute__((address_space(1))) void*)kg0,
        (__attribute__((address_space(3))) void*)kl, 16, 0, 0);
    __builtin_amdgcn_global_load_lds((const __attribute__((address_space(1))) void*)kg1,
        (__attribute__((address_space(3))) void*)(kl + 1024), 16, 0, 0);
    __builtin_amdgcn_global_load_lds((const __attribute__((address_space(1))) void*)vg0,
        (__attribute__((address_space(3))) void*)vl, 16, 0, 0);
    __builtin_amdgcn_global_load_lds((const __attribute__((address_space(1))) void*)vg1,
        (__attribute__((address_space(3))) void*)(vl + 1024), 16, 0, 0);
  };

  stage(0, 0);
  __syncthreads();   // tile 0 ready (barrier drains vmcnt)

  for (int kb = 0; kb < nblk; ++kb) {
    int cur = kb & 1;
    int kbase = kb * 64;
    if (kb + 1 < nblk) stage(1 - cur, (kb + 1) * 64);   // flies during compute

    if (kbase < wmax) {   // wave-uniform: skip fully-masked tiles for this wave
      // ---- QK^T: 64 keys, swapped operands ----
      facc z[4] = {};
#pragma unroll
      for (int gg = 0; gg < 2; ++gg) {
        int ra = gg * 32 + krow0;
        int rb = ra + 4;
        const char* Kc = (const char*)&Kt[cur][0];
        bfrag a0 = *(const bfrag*)(Kc + ra * 128 + ((g * 16) ^ SWZ(ra)));
        bfrag a1 = *(const bfrag*)(Kc + ra * 128 + ((g * 16 + 64) ^ SWZ(ra)));
        z[2 * gg] = __builtin_amdgcn_mfma_f32_16x16x32_bf16(a0, qf0, z[2 * gg], 0, 0, 0);
        z[2 * gg] = __builtin_amdgcn_mfma_f32_16x16x32_bf16(a1, qf1, z[2 * gg], 0, 0, 0);
        bfrag a2 = *(const bfrag*)(Kc + rb * 128 + ((g * 16) ^ SWZ(rb)));
        bfrag a3 = *(const bfrag*)(Kc + rb * 128 + ((g * 16 + 64) ^ SWZ(rb)));
        z[2 * gg + 1] = __builtin_amdgcn_mfma_f32_16x16x32_bf16(a2, qf0, z[2 * gg + 1], 0, 0, 0);
        z[2 * gg + 1] = __builtin_amdgcn_mfma_f32_16x16x32_bf16(a3, qf1, z[2 * gg + 1], 0, 0, 0);
      }

      // lane holds 16 keys: sv[8*gg + c] <-> j = kbase + 32*gg + 8*g + c
      float sv[16];
#pragma unroll
      for (int gg = 0; gg < 2; ++gg)
#pragma unroll
        for (int c = 0; c < 4; ++c) {
          sv[8 * gg + c] = z[2 * gg][c];
          sv[8 * gg + 4 + c] = z[2 * gg + 1][c];
        }
      if (kbase + 64 > wmin) {   // boundary tile: apply element masks
#pragma unroll
        for (int gg = 0; gg < 2; ++gg)
#pragma unroll
          for (int c = 0; c < 8; ++c) {
            int j = kbase + 32 * gg + 8 * g + c;
            if (j >= jlim) sv[8 * gg + c] = -1e12f;
          }
      }

      float mx = sv[0];
#pragma unroll
      for (int c = 1; c < 16; ++c) mx = fmaxf(mx, sv[c]);
      mx = fmaxf(mx, __shfl_xor(mx, 16, 64));
      mx = fmaxf(mx, __shfl_xor(mx, 32, 64));
      float nm = fmaxf(mrow, mx);
      float sc = exp2f(mrow - nm);
      alignas(16) bf16 pb[16];
      float ss = 0.f;
#pragma unroll
      for (int c = 0; c < 16; ++c) {
        float pv = exp2f(sv[c] - nm);
        ss += pv;
        pb[c] = __float2bfloat16(pv);
      }
      ss += __shfl_xor(ss, 16, 64);
      ss += __shfl_xor(ss, 32, 64);
      lrow = lrow * sc + ss;
      mrow = nm;
#pragma unroll
      for (int t = 0; t < 4; ++t)
#pragma unroll
        for (int r = 0; r < 4; ++r) o[t][r] *= sc;

      // ---- PV: o[t] += V^T x P, V from swizzled LDS ----
      bfrag pf0 = *(const bfrag*)&pb[0];
      bfrag pf1 = *(const bfrag*)&pb[8];
      const char* Vc = (const char*)&Vt[cur][0];
#pragma unroll
      for (int t = 0; t < 4; ++t) {
        int d = t * 16 + l15;
        bfrag vf0 = *(const bfrag*)(Vc + d * 128 + ((g * 16) ^ SWZ(d)));
        bfrag vf1 = *(const bfrag*)(Vc + d * 128 + ((g * 16 + 64) ^ SWZ(d)));
        o[t] = __builtin_amdgcn_mfma_f32_16x16x32_bf16(vf0, pf0, o[t], 0, 0, 0);
        o[t] = __builtin_amdgcn_mfma_f32_16x16x32_bf16(vf1, pf1, o[t], 0, 0, 0);
      }
    }

    __syncthreads();   // drains next-tile stage (overlapped with compute) + syncs buffers
  }

  float inv = 1.0f / lrow;
  if (qrow >= Ql) inv = 0.f;     // query-length mask
#pragma unroll
  for (int t = 0; t < 4; ++t) {
    f4 ov;
#pragma unroll
    for (int r = 0; r < 4; ++r) ov[r] = o[t][r] * inv;
    *(f4*)&out[((size_t)b * S_ + qrow) * (H_ * DH_) + h * DH_ + t * 16 + g * 4] = ov;
  }
}

extern "C" void kernel_launch(void* const* d_in, const int* in_sizes, int n_in,
                              void* d_out, int out_size, void* d_ws, size_t ws_size,
                              hipStream_t stream) {
  const float* Qs = (const float*)d_in[0];
  const float* Ks = (const float*)d_in[1];
  const float* Vs = (const float*)d_in[2];
  const int* Qlen = (const int*)d_in[3];
  const int* Vlen = (const int*)d_in[4];
  const float* WQ = (const float*)d_in[5];
  const float* WK = (const float*)d_in[6];
  const float* WV = (const float*)d_in[7];
  float* out = (float*)d_out;

  char* ws = (char*)d_ws;
  const size_t MB = 1024 * 1024;
  bf16* wqT = (bf16*)(ws + 0 * MB);
  bf16* wkT = (bf16*)(ws + 2 * MB);
  bf16* wvT = (bf16*)(ws + 4 * MB);
  bf16* qb  = (bf16*)(ws + 6 * MB);    // (B,H,S,DH)
  bf16* kb  = (bf16*)(ws + 22 * MB);
  bf16* vb  = (bf16*)(ws + 38 * MB);   // (B,H,DH,S)

  dim3 tb(256);
  // fold 1/sqrt(64) * log2(e) into WQ^T -> QK^T scores land in log2 domain
  transpose_w<<<dim3(32, 32), tb, 0, stream>>>(WQ, wqT, 0.125f * 1.44269504f);
  transpose_w<<<dim3(32, 32), tb, 0, stream>>>(WK, wkT, 1.0f);
  transpose_w<<<dim3(32, 32), tb, 0, stream>>>(WV, wvT, 1.0f);

  proj_gemm<0><<<dim3(64, 8), tb, 0, stream>>>(Qs, wqT, qb);
  proj_gemm<0><<<dim3(64, 8), tb, 0, stream>>>(Ks, wkT, kb);
  proj_gemm<1><<<dim3(64, 8), tb, 0, stream>>>(Vs, wvT, vb);

  attn_fwd<<<dim3(B_ * H_ * (S_ / 64)), tb, 0, stream>>>(qb, kb, vb, Qlen, Vlen, out);
}

// Round 7
// 148.326 us; speedup vs baseline: 1.6626x; 1.1000x over previous
//
#include <hip/hip_runtime.h>
#include <hip/hip_bf16.h>
#include <stdint.h>

#define H_ 16
#define DH_ 64
#define B_ 8
#define S_ 1024
#define D_ 1024

using bf16 = __hip_bfloat16;
typedef __attribute__((ext_vector_type(8))) short bfrag;   // 8 x bf16 (16B) MFMA A/B frag
typedef __attribute__((ext_vector_type(4))) float facc;    // 4 x f32 MFMA C/D frag
typedef __attribute__((ext_vector_type(4))) float f4;

#define SWZ(r) ((((r) & 7) << 4) ^ (((r) & 8) << 3))   // attn: 128B rows
#define SWZP(r) ((((r) >> 1) & 3) << 4)                 // proj: 64B rows, 16B slots

// ---------------- W transpose f32->bf16 (+ scale folded in) ----------------
__global__ __launch_bounds__(256) void transpose_w(const float* __restrict__ W,
                                                   bf16* __restrict__ WT,
                                                   float scale) {
  __shared__ bf16 tile[32][33];
  int tx = threadIdx.x & 31, ty = threadIdx.x >> 5;  // 32 x 8
  int bx = blockIdx.x, by = blockIdx.y;
#pragma unroll
  for (int i = 0; i < 4; ++i) {
    int kk = by * 32 + ty + 8 * i;
    int nn = bx * 32 + tx;
    tile[ty + 8 * i][tx] = __float2bfloat16(W[kk * D_ + nn] * scale);
  }
  __syncthreads();
#pragma unroll
  for (int i = 0; i < 4; ++i) {
    int nn = bx * 32 + ty + 8 * i;
    int kk = by * 32 + tx;
    WT[(size_t)nn * D_ + kk] = tile[tx][ty + 8 * i];
  }
}

// ---------------- Projection GEMM: f32 A (fused convert), dbuf, XOR-swizzled LDS ----------------
// A: (8192, 1024) f32 row-major; Bt: (1024 n, 1024 k) bf16 row-major (W^T)
// MODE 0: C[m,n] -> out (B,H,S,DH) ; MODE 1: C[m,n] -> out (B,H,DH,S)
template <int MODE>
__global__ __launch_bounds__(256) void proj_gemm(const float* __restrict__ A,
                                                 const bf16* __restrict__ Bt,
                                                 bf16* __restrict__ out) {
  __shared__ __align__(16) bf16 As[2][128][32];
  __shared__ __align__(16) bf16 Bs[2][128][32];
  int tid = threadIdx.x;
  int lane = tid & 63;
  int wave = tid >> 6;
  int m0 = blockIdx.x * 128;
  int n0 = blockIdx.y * 128;
  int wm = (wave >> 1) * 64;
  int wn = (wave & 1) * 64;
  int l15 = lane & 15, l4 = lane >> 4;
  // A reg-staging: thread tid covers rows {ar, ar+64}, 8 f32 cols each
  int ar = tid >> 2;
  int aslot = tid & 3;                 // logical 16B slot (8 bf16)
  int ac = aslot * 8;
  // B gload_lds staging: row br within 16-row group; source col pre-swizzled
  int br = lane >> 2;
  int bslot_log = (lane & 3) ^ ((br >> 1) & 3);   // content for physical slot lane&3
  int bc = bslot_log * 8;

  facc acc[4][4] = {};
  f4 ap[4];   // A f32 in flight (16 f32)

  auto issueA = [&](int k0) {
    const float* s0 = &A[(size_t)(m0 + ar) * D_ + k0 + ac];
    ap[0] = *(const f4*)s0;
    ap[1] = *(const f4*)(s0 + 4);
    const float* s1 = &A[(size_t)(m0 + 64 + ar) * D_ + k0 + ac];
    ap[2] = *(const f4*)s1;
    ap[3] = *(const f4*)(s1 + 4);
  };
  auto issueB = [&](int buf, int k0) {
#pragma unroll
    for (int c = 0; c < 2; ++c) {
      int row = wave * 32 + c * 16;
      __builtin_amdgcn_global_load_lds(
          (const __attribute__((address_space(1))) void*)&Bt[(size_t)(n0 + row + br) * D_ + k0 + bc],
          (__attribute__((address_space(3))) void*)&Bs[buf][row][0], 16, 0, 0);
    }
  };
  auto writeA = [&](int buf) {
    alignas(16) bf16 t0[8], t1[8];
#pragma unroll
    for (int j = 0; j < 4; ++j) {
      t0[j] = __float2bfloat16(ap[0][j]);
      t0[4 + j] = __float2bfloat16(ap[1][j]);
      t1[j] = __float2bfloat16(ap[2][j]);
      t1[4 + j] = __float2bfloat16(ap[3][j]);
    }
    // physical slot = logical ^ ((row>>1)&3); bijective per row -> conflict-free
    char* base = (char*)&As[buf][0][0];
    *(bfrag*)(base + ar * 64 + ((aslot * 16) ^ SWZP(ar))) = *(const bfrag*)t0;
    *(bfrag*)(base + (ar + 64) * 64 + ((aslot * 16) ^ SWZP(ar + 64))) = *(const bfrag*)t1;
  };

  // prologue: stage k-step 0 into buf 0
  issueA(0);
  issueB(0, 0);
  writeA(0);
  __syncthreads();

  for (int kt = 0; kt < 32; ++kt) {
    int cur = kt & 1;
    if (kt < 31) {
      issueA((kt + 1) * 32);
      issueB(1 - cur, (kt + 1) * 32);
    }
    bfrag af[4], bfr[4];
    const char* Ab = (const char*)&As[cur][0][0];
    const char* Bb = (const char*)&Bs[cur][0][0];
#pragma unroll
    for (int i = 0; i < 4; ++i) {
      int row = wm + i * 16 + l15;
      af[i] = *(const bfrag*)(Ab + row * 64 + ((l4 * 16) ^ SWZP(row)));
    }
#pragma unroll
    for (int j = 0; j < 4; ++j) {
      int row = wn + j * 16 + l15;
      bfr[j] = *(const bfrag*)(Bb + row * 64 + ((l4 * 16) ^ SWZP(row)));
    }
#pragma unroll
    for (int i = 0; i < 4; ++i)
#pragma unroll
      for (int j = 0; j < 4; ++j)
        acc[i][j] = __builtin_amdgcn_mfma_f32_16x16x32_bf16(af[i], bfr[j], acc[i][j], 0, 0, 0);
    if (kt < 31) writeA(1 - cur);
    __syncthreads();
  }

  // epilogue: C/D layout col = lane&15, row = (lane>>4)*4 + reg
#pragma unroll
  for (int i = 0; i < 4; ++i)
#pragma unroll
    for (int j = 0; j < 4; ++j)
#pragma unroll
      for (int r = 0; r < 4; ++r) {
        int gm = m0 + wm + i * 16 + l4 * 4 + r;
        int gn = n0 + wn + j * 16 + l15;
        int b = gm >> 10, s = gm & (S_ - 1);
        int h = gn >> 6, dh = gn & 63;
        bf16 val = __float2bfloat16(acc[i][j][r]);
        if (MODE == 0)
          out[(((size_t)b * H_ + h) * S_ + s) * DH_ + dh] = val;
        else
          out[(((size_t)b * H_ + h) * DH_ + dh) * S_ + s] = val;
      }
}

// ---------------- Flash attention: dbuf LDS K/V, swapped-QK^T, LPT order, defer-max ----------------
// q,k: (B,H,S,DH) bf16 (q pre-scaled by log2e/8); vT: (B,H,DH,S) bf16; out: (B,S,H*DH) f32
__global__ __launch_bounds__(256) void attn_fwd(const bf16* __restrict__ q,
                                                const bf16* __restrict__ k,
                                                const bf16* __restrict__ vT,
                                                const int* __restrict__ Qlen,
                                                const int* __restrict__ Vlen,
                                                float* __restrict__ out) {
  __shared__ __align__(16) bf16 Kt[2][64 * 64];   // 8 KB each, row=key, XOR-swizzled
  __shared__ __align__(16) bf16 Vt[2][64 * 64];   // 8 KB each, row=d,   XOR-swizzled
  int tid = threadIdx.x, lane = tid & 63, wave = tid >> 6;
  int bid = blockIdx.x;
  int h = bid & 15, b = (bid >> 4) & 7;
  int qt = 15 - (bid >> 7);   // LPT: longest blocks (big qt) dispatch FIRST; qt in [0,15]
  int q0b = qt * 64;
  int q0 = q0b + wave * 16;
  const bf16* qp = q + (size_t)(b * H_ + h) * S_ * DH_;
  const bf16* kp = k + (size_t)(b * H_ + h) * S_ * DH_;
  const bf16* vp = vT + (size_t)(b * H_ + h) * DH_ * S_;
  int Vl = Vlen[b], Ql = Qlen[b];
  bool vzero = (Vl == 0);   // f32 ref: A-1e12 == -1e12 exactly -> exact uniform causal softmax
  int l15 = lane & 15, g = lane >> 4;
  int qrow = q0 + l15;

  // per-lane valid-key bound and wave-uniform tile bounds
  int jlim = vzero ? (qrow + 1) : min(qrow + 1, Vl);   // keys j < jlim are live
  int wmin = vzero ? (q0 + 1) : min(q0 + 1, Vl);
  int wmax = vzero ? (q0 + 16) : min(q0 + 16, Vl);

  // Q as B-operand: col = lane&15 = q, d = g*8 + j   (scores in log2 domain)
  bfrag qf0 = *(const bfrag*)&qp[(q0 + l15) * DH_ + g * 8];
  bfrag qf1 = *(const bfrag*)&qp[(q0 + l15) * DH_ + 32 + g * 8];
  if (vzero) {   // scores := 0 -> exact uniform weights over causal window
#pragma unroll
    for (int i = 0; i < 8; ++i) { qf0[i] = 0; qf1[i] = 0; }
  }

  facc o[4] = {};              // O^T accum: col=q(lane&15), row d = 16t + 4g + r
  float mrow = -1e30f, lrow = 0.f;

  int kendb = q0b + 64;
  if (!vzero) kendb = kendb < Vl ? kendb : Vl;
  int nblk = (kendb + 63) >> 6;

  // permuted K A-row: A-row r holds key 8*(r>>2)+(r&3)
  int krow0 = 8 * (l15 >> 2) + (l15 & 3);
  // staging: lane stages rows sr0, sr0+8 at byte sbb (pre-swizzled source, linear LDS dest)
  int sr0 = wave * 16 + (lane >> 3);
  int sbb = (lane & 7) * 16;

  auto stage = [&](int buf, int kbase) {
    int r0 = sr0, r1 = sr0 + 8;
    const char* kg0 = (const char*)(kp + (size_t)(kbase + r0) * DH_) + (sbb ^ SWZ(r0));
    const char* kg1 = (const char*)(kp + (size_t)(kbase + r1) * DH_) + (sbb ^ SWZ(r1));
    const char* vg0 = (const char*)(vp + (size_t)r0 * S_ + kbase) + (sbb ^ SWZ(r0));
    const char* vg1 = (const char*)(vp + (size_t)r1 * S_ + kbase) + (sbb ^ SWZ(r1));
    char* kl = (char*)&Kt[buf][0] + wave * 2048;
    char* vl = (char*)&Vt[buf][0] + wave * 2048;
    __builtin_amdgcn_global_load_lds((const __attribute__((address_space(1))) void*)kg0,
        (__attribute__((address_space(3))) void*)kl, 16, 0, 0);
    __builtin_amdgcn_global_load_lds((const __attribute__((address_space(1))) void*)kg1,
        (__attribute__((address_space(3))) void*)(kl + 1024), 16, 0, 0);
    __builtin_amdgcn_global_load_lds((const __attribute__((address_space(1))) void*)vg0,
        (__attribute__((address_space(3))) void*)vl, 16, 0, 0);
    __builtin_amdgcn_global_load_lds((const __attribute__((address_space(1))) void*)vg1,
        (__attribute__((address_space(3))) void*)(vl + 1024), 16, 0, 0);
  };

  stage(0, 0);
  __syncthreads();

  for (int kb = 0; kb < nblk; ++kb) {
    int cur = kb & 1;
    int kbase = kb * 64;
    if (kb + 1 < nblk) stage(1 - cur, (kb + 1) * 64);   // flies during compute

    if (kbase < wmax) {   // wave-uniform: skip fully-masked tiles for this wave
      // ---- QK^T: 64 keys, swapped operands ----
      facc z[4] = {};
#pragma unroll
      for (int gg = 0; gg < 2; ++gg) {
        int ra = gg * 32 + krow0;
        int rb = ra + 4;
        const char* Kc = (const char*)&Kt[cur][0];
        bfrag a0 = *(const bfrag*)(Kc + ra * 128 + ((g * 16) ^ SWZ(ra)));
        bfrag a1 = *(const bfrag*)(Kc + ra * 128 + ((g * 16 + 64) ^ SWZ(ra)));
        z[2 * gg] = __builtin_amdgcn_mfma_f32_16x16x32_bf16(a0, qf0, z[2 * gg], 0, 0, 0);
        z[2 * gg] = __builtin_amdgcn_mfma_f32_16x16x32_bf16(a1, qf1, z[2 * gg], 0, 0, 0);
        bfrag a2 = *(const bfrag*)(Kc + rb * 128 + ((g * 16) ^ SWZ(rb)));
        bfrag a3 = *(const bfrag*)(Kc + rb * 128 + ((g * 16 + 64) ^ SWZ(rb)));
        z[2 * gg + 1] = __builtin_amdgcn_mfma_f32_16x16x32_bf16(a2, qf0, z[2 * gg + 1], 0, 0, 0);
        z[2 * gg + 1] = __builtin_amdgcn_mfma_f32_16x16x32_bf16(a3, qf1, z[2 * gg + 1], 0, 0, 0);
      }

      // lane holds 16 keys: sv[8*gg + c] <-> j = kbase + 32*gg + 8*g + c
      float sv[16];
#pragma unroll
      for (int gg = 0; gg < 2; ++gg)
#pragma unroll
        for (int c = 0; c < 4; ++c) {
          sv[8 * gg + c] = z[2 * gg][c];
          sv[8 * gg + 4 + c] = z[2 * gg + 1][c];
        }
      if (kbase + 64 > wmin) {   // boundary tile: apply element masks
#pragma unroll
        for (int gg = 0; gg < 2; ++gg)
#pragma unroll
          for (int c = 0; c < 8; ++c) {
            int j = kbase + 32 * gg + 8 * g + c;
            if (j >= jlim) sv[8 * gg + c] = -1e12f;
          }
      }

      // local max (clang fuses nested fmaxf -> v_max3)
      float mxl = sv[0];
#pragma unroll
      for (int c = 1; c < 16; ++c) mxl = fmaxf(mxl, sv[c]);

      // T13 defer-max: skip rescale when max didn't grow past threshold (log2 domain)
      if (!__all(mxl <= mrow + 8.0f)) {
        float mx = fmaxf(mxl, __shfl_xor(mxl, 16, 64));
        mx = fmaxf(mx, __shfl_xor(mx, 32, 64));
        float nm = fmaxf(mrow, mx);
        float sc = exp2f(mrow - nm);
        lrow *= sc;
#pragma unroll
        for (int t = 0; t < 4; ++t)
#pragma unroll
          for (int r = 0; r < 4; ++r) o[t][r] *= sc;
        mrow = nm;
      }

      alignas(16) bf16 pb[16];
      float ss = 0.f;
#pragma unroll
      for (int c = 0; c < 16; ++c) {
        float pv = exp2f(sv[c] - mrow);
        ss += pv;
        pb[c] = __float2bfloat16(pv);
      }
      ss += __shfl_xor(ss, 16, 64);
      ss += __shfl_xor(ss, 32, 64);
      lrow += ss;

      // ---- PV: o[t] += V^T x P, V from swizzled LDS ----
      bfrag pf0 = *(const bfrag*)&pb[0];
      bfrag pf1 = *(const bfrag*)&pb[8];
      const char* Vc = (const char*)&Vt[cur][0];
#pragma unroll
      for (int t = 0; t < 4; ++t) {
        int d = t * 16 + l15;
        bfrag vf0 = *(const bfrag*)(Vc + d * 128 + ((g * 16) ^ SWZ(d)));
        bfrag vf1 = *(const bfrag*)(Vc + d * 128 + ((g * 16 + 64) ^ SWZ(d)));
        o[t] = __builtin_amdgcn_mfma_f32_16x16x32_bf16(vf0, pf0, o[t], 0, 0, 0);
        o[t] = __builtin_amdgcn_mfma_f32_16x16x32_bf16(vf1, pf1, o[t], 0, 0, 0);
      }
    }

    __syncthreads();   // drains next-tile stage (overlapped with compute) + syncs buffers
  }

  float inv = 1.0f / lrow;
  if (qrow >= Ql) inv = 0.f;     // query-length mask
#pragma unroll
  for (int t = 0; t < 4; ++t) {
    f4 ov;
#pragma unroll
    for (int r = 0; r < 4; ++r) ov[r] = o[t][r] * inv;
    *(f4*)&out[((size_t)b * S_ + qrow) * (H_ * DH_) + h * DH_ + t * 16 + g * 4] = ov;
  }
}

extern "C" void kernel_launch(void* const* d_in, const int* in_sizes, int n_in,
                              void* d_out, int out_size, void* d_ws, size_t ws_size,
                              hipStream_t stream) {
  const float* Qs = (const float*)d_in[0];
  const float* Ks = (const float*)d_in[1];
  const float* Vs = (const float*)d_in[2];
  const int* Qlen = (const int*)d_in[3];
  const int* Vlen = (const int*)d_in[4];
  const float* WQ = (const float*)d_in[5];
  const float* WK = (const float*)d_in[6];
  const float* WV = (const float*)d_in[7];
  float* out = (float*)d_out;

  char* ws = (char*)d_ws;
  const size_t MB = 1024 * 1024;
  bf16* wqT = (bf16*)(ws + 0 * MB);
  bf16* wkT = (bf16*)(ws + 2 * MB);
  bf16* wvT = (bf16*)(ws + 4 * MB);
  bf16* qb  = (bf16*)(ws + 6 * MB);    // (B,H,S,DH)
  bf16* kb  = (bf16*)(ws + 22 * MB);
  bf16* vb  = (bf16*)(ws + 38 * MB);   // (B,H,DH,S)

  dim3 tb(256);
  // fold 1/sqrt(64) * log2(e) into WQ^T -> QK^T scores land in log2 domain
  transpose_w<<<dim3(32, 32), tb, 0, stream>>>(WQ, wqT, 0.125f * 1.44269504f);
  transpose_w<<<dim3(32, 32), tb, 0, stream>>>(WK, wkT, 1.0f);
  transpose_w<<<dim3(32, 32), tb, 0, stream>>>(WV, wvT, 1.0f);

  proj_gemm<0><<<dim3(64, 8), tb, 0, stream>>>(Qs, wqT, qb);
  proj_gemm<0><<<dim3(64, 8), tb, 0, stream>>>(Ks, wkT, kb);
  proj_gemm<1><<<dim3(64, 8), tb, 0, stream>>>(Vs, wvT, vb);

  attn_fwd<<<dim3(B_ * H_ * (S_ / 64)), tb, 0, stream>>>(qb, kb, vb, Qlen, Vlen, out);
}